// Round 10
// baseline (285.302 us; speedup 1.0000x reference)
//
#include <hip/hip_runtime.h>
#include <math.h>

#define N_PTS   8192
#define NBATCH  4
#define NQ      (N_PTS*NBATCH)   // 32768
#define GFN     100
#define KNN     10
#define NSPLIT  16
#define SPLITL  (N_PTS/NSPLIT)   // 512
#define QPL     2                // queries per lane in knn
#define MBLK    64               // points per mlp1 block
#define WROW    112              // padded weight row: 4 chunks * 28 floats

__device__ __forceinline__ float med3f(float a, float b, float c){
  return __builtin_amdgcn_fmed3f(a, b, c);
}

// sorted insert of d into ascending m[0..9], dropping the largest. no-op if d>=m[9].
__device__ __forceinline__ void insert10(float (&m)[KNN], float d){
  #pragma unroll
  for (int k = KNN-1; k > 0; k--) m[k] = med3f(d, m[k-1], m[k]);
  m[0] = fminf(m[0], d);
}

__device__ __forceinline__ void ld7(float4 (&w)[7], const float* base){
  const float4* v = reinterpret_cast<const float4*>(base);
  #pragma unroll
  for (int i = 0; i < 7; i++) w[i] = v[i];
}

__device__ __forceinline__ void fma25(float (&acc)[25], float xv, const float4 (&w)[7]){
  #pragma unroll
  for (int i = 0; i < 6; i++){
    acc[i*4+0] = fmaf(xv, w[i].x, acc[i*4+0]);
    acc[i*4+1] = fmaf(xv, w[i].y, acc[i*4+1]);
    acc[i*4+2] = fmaf(xv, w[i].z, acc[i*4+2]);
    acc[i*4+3] = fmaf(xv, w[i].w, acc[i*4+3]);
  }
  acc[24] = fmaf(xv, w[6].x, acc[24]);
}

// ---------------- K0: repack weights (aligned padded chunks) + zero pool ----------------
__global__ __launch_bounds__(256) void prep_kernel(const float* __restrict__ w1b,
                                                   const float* __restrict__ w2,
                                                   float* __restrict__ w1bp,
                                                   float* __restrict__ w2p,
                                                   float* __restrict__ pool){
  const int t0 = blockIdx.x * 256 + threadIdx.x;
  const int stride = gridDim.x * 256;
  for (int i = t0; i < 20*WROW; i += stride){
    int c = i / WROW, j = i % WROW, ch = j / 28, k = j % 28;
    w1bp[i] = (k < 25) ? w1b[c*GFN + ch*25 + k] : 0.0f;
  }
  for (int i = t0; i < GFN*WROW; i += stride){
    int c = i / WROW, j = i % WROW, ch = j / 28, k = j % 28;
    w2p[i] = (k < 25) ? w2[c*GFN + ch*25 + k] : 0.0f;
  }
  for (int i = t0; i < NBATCH*GFN; i += stride) pool[i] = 0.0f;
}

// ---------------- K1: KNN top-10, 16-way split, 2 queries/lane ----------------
// QPL=2: 4096 waves (4 blocks/CU, ~4 waves/SIMD) — occupancy experiment vs R9's
// QPL=4 (2048 waves, 1.4/SIMD). Same total insert work, same cand size.
__global__ __launch_bounds__(256) void knn_kernel(const float* __restrict__ x,
                                                  float* __restrict__ cand){
  __shared__ float4 tile[SPLITL];   // 8 KB
  const int t   = threadIdx.x;
  const int w   = t >> 6;
  const int p   = t & 63;
  const int s   = blockIdx.y;       // 0..15
  const int qb0 = blockIdx.x * (256*QPL);  // block covers 512 queries
  const int b   = qb0 >> 13;
  const float* xb = x + (size_t)b * N_PTS * 3;

  // stage 512 points, thread t writes points {t, t+256} (lane-consecutive)
  #pragma unroll
  for (int k = 0; k < 2; k++){
    const int j = t + 256*k;
    const float* ps = xb + (size_t)(s*SPLITL + j)*3;
    float px = ps[0], py = ps[1], pz = ps[2];
    tile[j] = make_float4(px, py, pz, fmaf(pz, pz, fmaf(py, py, px*px)));
  }
  __syncthreads();

  float qx[QPL], qy[QPL], qz[QPL], qs[QPL];
  #pragma unroll
  for (int u = 0; u < QPL; u++){
    const int q = qb0 + w*(64*QPL) + u*64 + p;
    qx[u] = x[(size_t)q*3+0];
    qy[u] = x[(size_t)q*3+1];
    qz[u] = x[(size_t)q*3+2];
    qs[u] = fmaf(qz[u], qz[u], fmaf(qy[u], qy[u], qx[u]*qx[u]));
  }

  float m[QPL][KNN];
  #pragma unroll
  for (int u = 0; u < QPL; u++)
    #pragma unroll
    for (int k = 0; k < KNN; k++) m[u][k] = INFINITY;

  #pragma unroll 4
  for (int j = 0; j < SPLITL; j++){
    float4 pt = tile[j];
    #pragma unroll
    for (int u = 0; u < QPL; u++){
      float dot = fmaf(qz[u], pt.z, fmaf(qy[u], pt.y, qx[u]*pt.x));
      float d   = fmaf(-2.0f, dot, qs[u] + pt.w);
      insert10(m[u], d);
    }
  }

  #pragma unroll
  for (int u = 0; u < QPL; u++){
    const int q = qb0 + w*(64*QPL) + u*64 + p;
    #pragma unroll
    for (int k = 0; k < KNN; k++) cand[(size_t)(s*KNN + k)*NQ + q] = m[u][k];
  }
}

// ------------- K2: merge, conv1 (13->20->100), conv2 (100->100) + pool -------------
// 256 threads = 4 waves, 64 points (all waves share the same points).
// Phase A: wave g merges lists [g*40, g*40+40) -> LDS partials; after one barrier
// EVERY wave merges the 4 partials and computes t20[20] IN REGISTERS (redundant
// across waves; kills the t20 LDS + one barrier). Phase B/C: wave g owns channel
// chunk [g*25, g*25+25), weights via 7 aligned float4 loads (prep-packed).
__global__ __launch_bounds__(256) void mlp1_kernel(
    const float* __restrict__ x,    const float* __restrict__ cand,
    const float* __restrict__ w1a,  const float* __restrict__ b1a,
    const float* __restrict__ w1bp, const float* __restrict__ b1b,
    const float* __restrict__ w2p,  const float* __restrict__ b2,
    float* __restrict__ x1t, float* __restrict__ pool){
  __shared__ float pa[4*MBLK*11];    // 11.3 KB partial top-10s (stride 11, odd)
  __shared__ float x1s[MBLK*101];    // 25.9 KB
  const int t = threadIdx.x;
  const int p = t & 63;
  const int g = __builtin_amdgcn_readfirstlane(t >> 6);  // 0..3
  const int q0 = blockIdx.x * MBLK;
  const int q  = q0 + p;
  const int b  = q0 >> 13;

  // ---- phase A: wave g merges its 40 candidate lists ----
  float m[KNN];
  #pragma unroll
  for (int k = 0; k < KNN; k++) m[k] = INFINITY;
  {
    const int i0 = g*40;
    #pragma unroll 8
    for (int i = i0; i < i0+40; i++) insert10(m, cand[(size_t)i*NQ + q]);
    #pragma unroll
    for (int k = 0; k < KNN; k++) pa[(g*MBLK+p)*11 + k] = m[k];
  }
  __syncthreads();

  // every wave: merge other 3 partials (own still in regs) + front-end in regs
  #pragma unroll
  for (int s2 = 0; s2 < 4; s2++){
    if (s2 != g){
      #pragma unroll
      for (int k = 0; k < KNN; k++) insert10(m, pa[(s2*MBLK+p)*11 + k]);
    }
  }

  float h[13];
  h[0] = x[(size_t)q*3+0]; h[1] = x[(size_t)q*3+1]; h[2] = x[(size_t)q*3+2];
  #pragma unroll
  for (int k = 0; k < KNN; k++) h[3+k] = m[k];

  float t20[20];
  #pragma unroll
  for (int o = 0; o < 20; o++) t20[o] = b1a[o];
  #pragma unroll
  for (int c = 0; c < 13; c++){
    float hv = h[c];
    #pragma unroll
    for (int o = 0; o < 20; o++) t20[o] = fmaf(hv, w1a[c*20+o], t20[o]);
  }
  #pragma unroll
  for (int o = 0; o < 20; o++) t20[o] = fmaxf(t20[o], 0.0f);

  const int o0 = g * 25;
  float acc[25];

  // ---- phase B: x1 = relu(t20 @ w1b + b1b), t20 from registers ----
  #pragma unroll
  for (int k = 0; k < 25; k++) acc[k] = b1b[o0+k];
  #pragma unroll 2
  for (int c = 0; c < 20; c++){
    float4 wv[7];
    ld7(wv, w1bp + c*WROW + g*28);
    fma25(acc, t20[c], wv);
  }
  #pragma unroll
  for (int k = 0; k < 25; k++){
    float v = fmaxf(acc[k], 0.0f);
    x1s[p*101 + o0 + k] = v;
    x1t[(size_t)(o0+k)*NQ + q] = v;    // coalesced (lanes q consecutive)
  }
  __syncthreads();

  // ---- phase C: x2 = relu(x1 @ w2 + b2), 2-deep weight dbuf ----
  #pragma unroll
  for (int k = 0; k < 25; k++) acc[k] = b2[o0+k];
  {
    float4 A[7], Bv[7];
    ld7(A, w2p + 0*WROW + g*28);
    #pragma unroll 1
    for (int c = 0; c < GFN; c += 2){
      ld7(Bv, w2p + (c+1)*WROW + g*28);
      float xv = x1s[p*101 + c];
      fma25(acc, xv, A);
      if (c + 2 < GFN) ld7(A, w2p + (c+2)*WROW + g*28);
      float xv2 = x1s[p*101 + c + 1];
      fma25(acc, xv2, Bv);
    }
  }
  #pragma unroll
  for (int k = 0; k < 25; k++){
    float v = fmaxf(acc[k], 0.0f);
    #pragma unroll
    for (int off = 1; off < 64; off <<= 1) v += __shfl_xor(v, off);
    if (p == 0) atomicAdd(&pool[b*GFN + o0 + k], v);
  }
}

// ---------------- K3: head (200->20->10->2) + log_softmax ----------------
// x1t column-major: every load is 64 consecutive dwords (fully coalesced).
__global__ __launch_bounds__(128) void head_kernel(
    const float* __restrict__ x1t, const float* __restrict__ pool,
    const float* __restrict__ w3a, const float* __restrict__ b3a,
    const float* __restrict__ w3b, const float* __restrict__ b3b,
    const float* __restrict__ w3c, const float* __restrict__ b3c,
    float* __restrict__ out){
  __shared__ float poolm[GFN];
  __shared__ float poolpart[20];
  const int t = threadIdx.x;
  const int q = blockIdx.x * 128 + t;
  const int b = q >> 13;

  if (t < GFN) poolm[t] = pool[b*GFN+t] * (1.0f / (float)N_PTS);
  __syncthreads();
  if (t < 20){
    float a = b3a[t];
    for (int c = 0; c < GFN; c++) a = fmaf(poolm[c], w3a[(GFN+c)*20+t], a);
    poolpart[t] = a;
  }
  __syncthreads();

  float acc[20];
  #pragma unroll
  for (int o = 0; o < 20; o++) acc[o] = 0.0f;
  #pragma unroll 8
  for (int c = 0; c < GFN; c++){
    float xv = x1t[(size_t)c*NQ + q];
    #pragma unroll
    for (int o = 0; o < 20; o++) acc[o] = fmaf(xv, w3a[c*20+o], acc[o]);
  }
  float o1[20];
  #pragma unroll
  for (int o = 0; o < 20; o++) o1[o] = fmaxf(acc[o] + poolpart[o], 0.0f);

  float o2[10];
  #pragma unroll
  for (int o = 0; o < 10; o++){
    float a = b3b[o];
    #pragma unroll
    for (int c = 0; c < 20; c++) a = fmaf(o1[c], w3b[c*10+o], a);
    o2[o] = fmaxf(a, 0.0f);
  }
  float e0 = b3c[0], e1 = b3c[1];
  #pragma unroll
  for (int c = 0; c < 10; c++){
    e0 = fmaf(o2[c], w3c[c*2+0], e0);
    e1 = fmaf(o2[c], w3c[c*2+1], e1);
  }
  float mx = fmaxf(e0, e1);
  float a0 = e0 - mx, a1 = e1 - mx;
  float lse = logf(expf(a0) + expf(a1));
  float2 r; r.x = a0 - lse; r.y = a1 - lse;
  *reinterpret_cast<float2*>(out + (size_t)q*2) = r;
}

extern "C" void kernel_launch(void* const* d_in, const int* in_sizes, int n_in,
                              void* d_out, int out_size, void* d_ws, size_t ws_size,
                              hipStream_t stream) {
  const float* x   = (const float*)d_in[0];
  const float* w1a = (const float*)d_in[1];
  const float* b1a = (const float*)d_in[2];
  const float* w1b = (const float*)d_in[3];
  const float* b1b = (const float*)d_in[4];
  const float* w2  = (const float*)d_in[5];
  const float* b2  = (const float*)d_in[6];
  const float* w3a = (const float*)d_in[7];
  const float* b3a = (const float*)d_in[8];
  const float* w3b = (const float*)d_in[9];
  const float* b3b = (const float*)d_in[10];
  const float* w3c = (const float*)d_in[11];
  const float* b3c = (const float*)d_in[12];
  float* out = (float*)d_out;

  char* ws = (char*)d_ws;
  size_t off = 0;
  float* cand = (float*)(ws + off); off += (size_t)NQ*NSPLIT*KNN*4;   // 21.0 MB
  float* x1t  = (float*)(ws + off); off += (size_t)NQ*GFN*4;          // 13.1 MB
  float* pool = (float*)(ws + off); off += 4096;
  float* w1bp = (float*)(ws + off); off += (size_t)20*WROW*4;         // 9 KB
  float* w2p  = (float*)(ws + off); off += (size_t)GFN*WROW*4;        // 44.8 KB

  prep_kernel<<<16, 256, 0, stream>>>(w1b, w2, w1bp, w2p, pool);
  knn_kernel<<<dim3(NQ/(256*QPL), NSPLIT), 256, 0, stream>>>(x, cand);
  mlp1_kernel<<<NQ/MBLK, 256, 0, stream>>>(x, cand, w1a, b1a, w1bp, b1b, w2p, b2, x1t, pool);
  head_kernel<<<NQ/128, 128, 0, stream>>>(x1t, pool, w3a, b3a, w3b, b3b, w3c, b3c, out);
}

// Round 11
// 275.683 us; speedup vs baseline: 1.0349x; 1.0349x over previous
//
#include <hip/hip_runtime.h>
#include <math.h>

#define N_PTS   8192
#define NBATCH  4
#define NQ      (N_PTS*NBATCH)   // 32768
#define GFN     100
#define KNN     10
#define NSPLIT  4
#define SPLITL  (N_PTS/NSPLIT)   // 2048
#define QPL     2                // queries per lane in knn
#define MBLK    64               // points per mlp1 block
#define WROW    112              // padded weight row: 4 chunks * 28 floats

__device__ __forceinline__ float med3f(float a, float b, float c){
  return __builtin_amdgcn_fmed3f(a, b, c);
}

// sorted insert of d into ascending m[0..9], dropping the largest. no-op if d>=m[9].
__device__ __forceinline__ void insert10(float (&m)[KNN], float d){
  #pragma unroll
  for (int k = KNN-1; k > 0; k--) m[k] = med3f(d, m[k-1], m[k]);
  m[0] = fminf(m[0], d);
}

__device__ __forceinline__ void ld7(float4 (&w)[7], const float* base){
  const float4* v = reinterpret_cast<const float4*>(base);
  #pragma unroll
  for (int i = 0; i < 7; i++) w[i] = v[i];
}

__device__ __forceinline__ void fma25(float (&acc)[25], float xv, const float4 (&w)[7]){
  #pragma unroll
  for (int i = 0; i < 6; i++){
    acc[i*4+0] = fmaf(xv, w[i].x, acc[i*4+0]);
    acc[i*4+1] = fmaf(xv, w[i].y, acc[i*4+1]);
    acc[i*4+2] = fmaf(xv, w[i].z, acc[i*4+2]);
    acc[i*4+3] = fmaf(xv, w[i].w, acc[i*4+3]);
  }
  acc[24] = fmaf(xv, w[6].x, acc[24]);
}

// ---------------- K1: KNN top-10, 4-way split, 2 queries/lane, QUAD processing ----------------
// Per quad of 4 points: min-tree (6 ops) + unconditional insert10 of quad-min;
// wave-voted rare path (~18% at 2048-scan) inserts the other three values.
// ~11 lane-ops/pair vs 15.5 branchless. Block (0,0) also packs w1b/w2 (prep).
__global__ __launch_bounds__(256) void knn_kernel(const float* __restrict__ x,
                                                  float* __restrict__ cand,
                                                  const float* __restrict__ w1b,
                                                  const float* __restrict__ w2,
                                                  float* __restrict__ w1bp,
                                                  float* __restrict__ w2p){
  __shared__ float4 tile[SPLITL];   // 32 KB
  const int t   = threadIdx.x;
  const int w   = t >> 6;
  const int p   = t & 63;
  const int s   = blockIdx.y;       // 0..3
  const int qb0 = blockIdx.x * (256*QPL);  // 512 queries per block
  const int b   = qb0 >> 13;
  const float* xb = x + (size_t)b * N_PTS * 3;

  // embedded prep (one block): pack weights into padded float4 rows
  if (blockIdx.x == 0 && s == 0){
    for (int i = t; i < 20*WROW; i += 256){
      int c = i / WROW, j = i % WROW, ch = j / 28, k = j % 28;
      w1bp[i] = (k < 25) ? w1b[c*GFN + ch*25 + k] : 0.0f;
    }
    for (int i = t; i < GFN*WROW; i += 256){
      int c = i / WROW, j = i % WROW, ch = j / 28, k = j % 28;
      w2p[i] = (k < 25) ? w2[c*GFN + ch*25 + k] : 0.0f;
    }
  }

  // stage 2048 points: thread t writes points {t+256k} (lane-consecutive)
  #pragma unroll
  for (int k = 0; k < 8; k++){
    const int j = t + 256*k;
    const float* ps = xb + (size_t)(s*SPLITL + j)*3;
    float px = ps[0], py = ps[1], pz = ps[2];
    tile[j] = make_float4(px, py, pz, fmaf(pz, pz, fmaf(py, py, px*px)));
  }
  __syncthreads();

  float qx[QPL], qy[QPL], qz[QPL], qs[QPL];
  #pragma unroll
  for (int u = 0; u < QPL; u++){
    const int q = qb0 + w*(64*QPL) + u*64 + p;
    qx[u] = x[(size_t)q*3+0];
    qy[u] = x[(size_t)q*3+1];
    qz[u] = x[(size_t)q*3+2];
    qs[u] = fmaf(qz[u], qz[u], fmaf(qy[u], qy[u], qx[u]*qx[u]));
  }

  float m[QPL][KNN];
  #pragma unroll
  for (int u = 0; u < QPL; u++)
    #pragma unroll
    for (int k = 0; k < KNN; k++) m[u][k] = INFINITY;

  for (int j = 0; j < SPLITL; j += 4){
    float4 p0 = tile[j], p1 = tile[j+1], p2 = tile[j+2], p3 = tile[j+3];
    #pragma unroll
    for (int u = 0; u < QPL; u++){
      float dot0 = fmaf(qz[u], p0.z, fmaf(qy[u], p0.y, qx[u]*p0.x));
      float dot1 = fmaf(qz[u], p1.z, fmaf(qy[u], p1.y, qx[u]*p1.x));
      float dot2 = fmaf(qz[u], p2.z, fmaf(qy[u], p2.y, qx[u]*p2.x));
      float dot3 = fmaf(qz[u], p3.z, fmaf(qy[u], p3.y, qx[u]*p3.x));
      float d0 = fmaf(-2.0f, dot0, qs[u] + p0.w);   // bit-identical to prior rounds
      float d1 = fmaf(-2.0f, dot1, qs[u] + p1.w);
      float d2 = fmaf(-2.0f, dot2, qs[u] + p2.w);
      float d3 = fmaf(-2.0f, dot3, qs[u] + p3.w);
      float m01 = fminf(d0, d1), m23 = fminf(d2, d3);
      float x01 = fmaxf(d0, d1), x23 = fmaxf(d2, d3);
      float mmin = fminf(m01, m23), mmax = fmaxf(m01, m23);
      insert10(m[u], mmin);                         // always
      float snd = fminf(fminf(x01, x23), mmax);     // 2nd-smallest of quad
      if (__any(snd < m[u][KNN-1])){                // rare: finish the quad
        insert10(m[u], mmax);
        insert10(m[u], x01);
        insert10(m[u], x23);
      }
    }
  }

  #pragma unroll
  for (int u = 0; u < QPL; u++){
    const int q = qb0 + w*(64*QPL) + u*64 + p;
    #pragma unroll
    for (int k = 0; k < KNN; k++) cand[(size_t)(s*KNN + k)*NQ + q] = m[u][k];
  }
}

// ------------- K2: merge, conv1 (13->20->100), conv2 (100->100) + block partial pool -------------
// 256 threads = 4 waves, 64 points. Phase A: wave g merges lists [g*10,g*10+10) -> LDS
// partials; every wave then merges the 4 partials and computes t20 in registers.
// Phases B/C: wave g owns channels [g*25,g*25+25), ld7 packed weights. Pool: per-block
// partial sums (no atomics) -> part[block][100].
__global__ __launch_bounds__(256) void mlp1_kernel(
    const float* __restrict__ x,    const float* __restrict__ cand,
    const float* __restrict__ w1a,  const float* __restrict__ b1a,
    const float* __restrict__ w1bp, const float* __restrict__ b1b,
    const float* __restrict__ w2p,  const float* __restrict__ b2,
    float* __restrict__ x1t, float* __restrict__ part){
  __shared__ float pa[4*MBLK*11];
  __shared__ float x1s[MBLK*101];
  const int t = threadIdx.x;
  const int p = t & 63;
  const int g = __builtin_amdgcn_readfirstlane(t >> 6);  // 0..3
  const int q0 = blockIdx.x * MBLK;
  const int q  = q0 + p;

  // phase A: wave g merges its 10 candidate lists
  float m[KNN];
  #pragma unroll
  for (int k = 0; k < KNN; k++) m[k] = INFINITY;
  {
    const int i0 = g*10;
    #pragma unroll
    for (int i = 0; i < 10; i++) insert10(m, cand[(size_t)(i0+i)*NQ + q]);
    #pragma unroll
    for (int k = 0; k < KNN; k++) pa[(g*MBLK+p)*11 + k] = m[k];
  }
  __syncthreads();

  #pragma unroll
  for (int s2 = 0; s2 < 4; s2++){
    if (s2 != g){
      #pragma unroll
      for (int k = 0; k < KNN; k++) insert10(m, pa[(s2*MBLK+p)*11 + k]);
    }
  }

  float h[13];
  h[0] = x[(size_t)q*3+0]; h[1] = x[(size_t)q*3+1]; h[2] = x[(size_t)q*3+2];
  #pragma unroll
  for (int k = 0; k < KNN; k++) h[3+k] = m[k];

  float t20[20];
  #pragma unroll
  for (int o = 0; o < 20; o++) t20[o] = b1a[o];
  #pragma unroll
  for (int c = 0; c < 13; c++){
    float hv = h[c];
    #pragma unroll
    for (int o = 0; o < 20; o++) t20[o] = fmaf(hv, w1a[c*20+o], t20[o]);
  }
  #pragma unroll
  for (int o = 0; o < 20; o++) t20[o] = fmaxf(t20[o], 0.0f);

  const int o0 = g * 25;
  float acc[25];

  // phase B: x1 = relu(t20 @ w1b + b1b)
  #pragma unroll
  for (int k = 0; k < 25; k++) acc[k] = b1b[o0+k];
  #pragma unroll 2
  for (int c = 0; c < 20; c++){
    float4 wv[7];
    ld7(wv, w1bp + c*WROW + g*28);
    fma25(acc, t20[c], wv);
  }
  #pragma unroll
  for (int k = 0; k < 25; k++){
    float v = fmaxf(acc[k], 0.0f);
    x1s[p*101 + o0 + k] = v;
    x1t[(size_t)(o0+k)*NQ + q] = v;    // coalesced
  }
  __syncthreads();

  // phase C: x2 = relu(x1 @ w2 + b2), 2-deep weight dbuf
  #pragma unroll
  for (int k = 0; k < 25; k++) acc[k] = b2[o0+k];
  {
    float4 A[7], Bv[7];
    ld7(A, w2p + 0*WROW + g*28);
    #pragma unroll 1
    for (int c = 0; c < GFN; c += 2){
      ld7(Bv, w2p + (c+1)*WROW + g*28);
      float xv = x1s[p*101 + c];
      fma25(acc, xv, A);
      if (c + 2 < GFN) ld7(A, w2p + (c+2)*WROW + g*28);
      float xv2 = x1s[p*101 + c + 1];
      fma25(acc, xv2, Bv);
    }
  }
  #pragma unroll
  for (int k = 0; k < 25; k++){
    float v = fmaxf(acc[k], 0.0f);
    #pragma unroll
    for (int off = 1; off < 64; off <<= 1) v += __shfl_xor(v, off);
    if (p == 0) part[(size_t)blockIdx.x*GFN + o0 + k] = v;   // no atomics
  }
}

// ---------------- K2b: reduce per-block pool partials ----------------
__global__ __launch_bounds__(128) void pool_reduce(const float* __restrict__ part,
                                                   float* __restrict__ pool){
  const int b = blockIdx.x;          // batch 0..3
  const int t = threadIdx.x;
  if (t < GFN){
    float s = 0.0f;
    #pragma unroll 8
    for (int i = 0; i < NQ/MBLK/NBATCH; i++)      // 128 blocks per batch
      s += part[(size_t)(b*(NQ/MBLK/NBATCH) + i)*GFN + t];
    pool[b*GFN + t] = s;
  }
}

// ---------------- K3: head (200->20->10->2) + log_softmax ----------------
__global__ __launch_bounds__(128) void head_kernel(
    const float* __restrict__ x1t, const float* __restrict__ pool,
    const float* __restrict__ w3a, const float* __restrict__ b3a,
    const float* __restrict__ w3b, const float* __restrict__ b3b,
    const float* __restrict__ w3c, const float* __restrict__ b3c,
    float* __restrict__ out){
  __shared__ float poolm[GFN];
  __shared__ float poolpart[20];
  const int t = threadIdx.x;
  const int q = blockIdx.x * 128 + t;
  const int b = q >> 13;

  if (t < GFN) poolm[t] = pool[b*GFN+t] * (1.0f / (float)N_PTS);
  __syncthreads();
  if (t < 20){
    float a = b3a[t];
    for (int c = 0; c < GFN; c++) a = fmaf(poolm[c], w3a[(GFN+c)*20+t], a);
    poolpart[t] = a;
  }
  __syncthreads();

  float acc[20];
  #pragma unroll
  for (int o = 0; o < 20; o++) acc[o] = 0.0f;
  #pragma unroll 8
  for (int c = 0; c < GFN; c++){
    float xv = x1t[(size_t)c*NQ + q];
    #pragma unroll
    for (int o = 0; o < 20; o++) acc[o] = fmaf(xv, w3a[c*20+o], acc[o]);
  }
  float o1[20];
  #pragma unroll
  for (int o = 0; o < 20; o++) o1[o] = fmaxf(acc[o] + poolpart[o], 0.0f);

  float o2[10];
  #pragma unroll
  for (int o = 0; o < 10; o++){
    float a = b3b[o];
    #pragma unroll
    for (int c = 0; c < 20; c++) a = fmaf(o1[c], w3b[c*10+o], a);
    o2[o] = fmaxf(a, 0.0f);
  }
  float e0 = b3c[0], e1 = b3c[1];
  #pragma unroll
  for (int c = 0; c < 10; c++){
    e0 = fmaf(o2[c], w3c[c*2+0], e0);
    e1 = fmaf(o2[c], w3c[c*2+1], e1);
  }
  float mx = fmaxf(e0, e1);
  float a0 = e0 - mx, a1 = e1 - mx;
  float lse = logf(expf(a0) + expf(a1));
  float2 r; r.x = a0 - lse; r.y = a1 - lse;
  *reinterpret_cast<float2*>(out + (size_t)q*2) = r;
}

extern "C" void kernel_launch(void* const* d_in, const int* in_sizes, int n_in,
                              void* d_out, int out_size, void* d_ws, size_t ws_size,
                              hipStream_t stream) {
  const float* x   = (const float*)d_in[0];
  const float* w1a = (const float*)d_in[1];
  const float* b1a = (const float*)d_in[2];
  const float* w1b = (const float*)d_in[3];
  const float* b1b = (const float*)d_in[4];
  const float* w2  = (const float*)d_in[5];
  const float* b2  = (const float*)d_in[6];
  const float* w3a = (const float*)d_in[7];
  const float* b3a = (const float*)d_in[8];
  const float* w3b = (const float*)d_in[9];
  const float* b3b = (const float*)d_in[10];
  const float* w3c = (const float*)d_in[11];
  const float* b3c = (const float*)d_in[12];
  float* out = (float*)d_out;

  char* ws = (char*)d_ws;
  size_t off = 0;
  float* cand = (float*)(ws + off); off += (size_t)NQ*NSPLIT*KNN*4;   // 5.24 MB
  float* x1t  = (float*)(ws + off); off += (size_t)NQ*GFN*4;          // 13.1 MB
  float* part = (float*)(ws + off); off += (size_t)(NQ/MBLK)*GFN*4;   // 205 KB
  float* pool = (float*)(ws + off); off += 4096;
  float* w1bp = (float*)(ws + off); off += (size_t)20*WROW*4;         // 9 KB
  float* w2p  = (float*)(ws + off); off += (size_t)GFN*WROW*4;        // 44.8 KB

  knn_kernel<<<dim3(NQ/(256*QPL), NSPLIT), 256, 0, stream>>>(x, cand, w1b, w2, w1bp, w2p);
  mlp1_kernel<<<NQ/MBLK, 256, 0, stream>>>(x, cand, w1a, b1a, w1bp, b1b, w2p, b2, x1t, part);
  pool_reduce<<<NBATCH, 128, 0, stream>>>(part, pool);
  head_kernel<<<NQ/128, 128, 0, stream>>>(x1t, pool, w3a, b3a, w3b, b3b, w3c, b3c, out);
}